// Round 3
// baseline (758.248 us; speedup 1.0000x reference)
//
#include <hip/hip_runtime.h>

// ---------------- problem constants ----------------
#define BATCH 8
#define CDIM  256
#define LSEQ  1024           // H*W = 32*32
#define DI    512            // d_inner
#define DS    16             // d_state
#define DR    16             // dt_rank
#define NTOK  (BATCH*LSEQ)   // 8192 tokens

// workspace layout (float offsets)
#define OFF_W2T 0                       // (256 c, 1024 j)  c-major
#define OFF_B2  262144                  // (1024)
#define OFF_WOT 263168                  // (512 d, 256 c)   d-major
#define OFF_XZ  394240                  // (8192 tok, 1024) xm|z
#define OFF_XS  8782848                 // (8192 tok, 512)
#define OFF_DT  12977152                // (8192 tok, 512)  (aliased by ygate)
#define OFF_BC  17171456                // (8192 tok, 32)   B|C
// total 17433600 floats = 69.7 MB

__device__ __forceinline__ float silu_f(float v) {
    return v / (1.f + __expf(-v));
}

// ---------- W2t[c][j] = sum_o in_proj_w[j,o]*proj_w[o,c] ----------
__global__ __launch_bounds__(256) void k_w2t(const float* __restrict__ ipw,
                                             const float* __restrict__ pw,
                                             float* __restrict__ W2t) {
    const int j = blockIdx.x;      // 0..1023
    const int c = threadIdx.x;     // 0..255
    float acc = 0.f;
    #pragma unroll 8
    for (int o = 0; o < 256; ++o)
        acc = fmaf(ipw[j*256 + o], pw[o*256 + c], acc);
    W2t[c*1024 + j] = acc;
}

// ---------- b2[j] = sum_o in_proj_w[j,o]*proj_b[o] ----------
__global__ __launch_bounds__(256) void k_b2(const float* __restrict__ ipw,
                                            const float* __restrict__ pb,
                                            float* __restrict__ b2) {
    const int j = blockIdx.x*256 + threadIdx.x;   // 0..1023
    float acc = 0.f;
    #pragma unroll 8
    for (int o = 0; o < 256; ++o)
        acc = fmaf(ipw[j*256 + o], pb[o], acc);
    b2[j] = acc;
}

// ---------- Wot[d][c] = out_proj_w[c][d] ----------
__global__ __launch_bounds__(512) void k_wot(const float* __restrict__ opw,
                                             float* __restrict__ Wot) {
    const int c = blockIdx.x;      // 0..255
    const int d = threadIdx.x;     // 0..511
    Wot[d*256 + c] = opw[c*512 + d];
}

// ---------- GEMM1: xz[tok][j] = sum_c W2t[c][j]*x[b,c,l] + b2[j] ----------
// M=8192 tokens (tile 128), N=1024 j (tile 128), K=256 (step 8)
__global__ __launch_bounds__(256) void k_gemm_xz(const float* __restrict__ x,
                                                 const float* __restrict__ W2t,
                                                 const float* __restrict__ b2,
                                                 float* __restrict__ xz) {
    __shared__ float As[8][128];
    __shared__ float Bs[8][128];
    const int tid = threadIdx.x;
    const int m0 = blockIdx.y * 128;          // token tile (within one b)
    const int n0 = blockIdx.x * 128;          // j tile
    const int b  = m0 >> 10;
    const int l0 = m0 & 1023;
    const float* xb = x + b*(256*1024);
    const int tx = tid & 15;                  // N dim
    const int ty = tid >> 4;                  // M dim
    float acc[8][8] = {};
    for (int c0 = 0; c0 < 256; c0 += 8) {
        __syncthreads();
        #pragma unroll
        for (int r = 0; r < 4; ++r) {
            int idx = r*256 + tid;
            int kk = idx >> 7, col = idx & 127;
            As[kk][col] = xb[(c0+kk)*1024 + l0 + col];
            Bs[kk][col] = W2t[(c0+kk)*1024 + n0 + col];
        }
        __syncthreads();
        #pragma unroll
        for (int kk = 0; kk < 8; ++kk) {
            float a[8], bb[8];
            #pragma unroll
            for (int i = 0; i < 8; ++i) a[i]  = As[kk][ty*8 + i];
            #pragma unroll
            for (int i = 0; i < 8; ++i) bb[i] = Bs[kk][tx*8 + i];
            #pragma unroll
            for (int i = 0; i < 8; ++i)
                #pragma unroll
                for (int j = 0; j < 8; ++j)
                    acc[i][j] = fmaf(a[i], bb[j], acc[i][j]);
        }
    }
    #pragma unroll
    for (int i = 0; i < 8; ++i) {
        const int tok = m0 + ty*8 + i;
        #pragma unroll
        for (int j = 0; j < 8; ++j) {
            const int jj = n0 + tx*8 + j;
            xz[(size_t)tok*1024 + jj] = acc[i][j] + b2[jj];
        }
    }
}

// ---------- depthwise causal conv(4) + bias + silu ----------
// xs[tok][d] = silu(conv_b[d] + sum_k w[d][k]*xm[tok-3+k][d])
__global__ __launch_bounds__(256) void k_conv(const float* __restrict__ xz,
                                              const float4* __restrict__ cw4,
                                              const float* __restrict__ cb,
                                              float* __restrict__ xs) {
    const int idx = blockIdx.x*256 + threadIdx.x;   // 0..4194303
    const int d = idx & 511;
    const int t = (idx >> 9) & 1023;
    const int b = idx >> 19;
    const float4 w = cw4[d];
    const float* base = xz + ((size_t)(b << 10)) * 1024 + d;  // xm part (j<512)
    float acc = cb[d];
    if (t >= 3) {
        acc = fmaf(w.x, base[(size_t)(t-3)*1024], acc);
        acc = fmaf(w.y, base[(size_t)(t-2)*1024], acc);
        acc = fmaf(w.z, base[(size_t)(t-1)*1024], acc);
        acc = fmaf(w.w, base[(size_t)t*1024], acc);
    } else {
        const float wk[4] = {w.x, w.y, w.z, w.w};
        #pragma unroll
        for (int k = 0; k < 4; ++k) {
            int tt = t - 3 + k;
            if (tt >= 0) acc = fmaf(wk[k], base[(size_t)tt*1024], acc);
        }
    }
    xs[idx] = acc * (1.f / (1.f + __expf(-acc)));
}

// ---------- fused x_proj + dt_proj + softplus ----------
// per block: 16 tokens. bc[tok][0:16]=B, [16:32]=C ; dtv=softplus(dt@dtw^T+dtb)
__global__ __launch_bounds__(256) void k_xdbl(const float* __restrict__ xs,
                                              const float* __restrict__ xpw,   // (48,512)
                                              const float* __restrict__ dtw,   // (512,16)
                                              const float* __restrict__ dtb,
                                              float* __restrict__ bcout,       // (tok,32)
                                              float* __restrict__ dtv) {
    __shared__ float xsT[16][512];
    __shared__ float xd[16][48];
    const int tid = threadIdx.x;
    const int tok0 = blockIdx.x * 16;
    #pragma unroll
    for (int r = 0; r < 32; ++r) {
        int idx = r*256 + tid;
        xsT[idx >> 9][idx & 511] = xs[(size_t)tok0*512 + idx];
    }
    __syncthreads();
    #pragma unroll
    for (int r = 0; r < 3; ++r) {
        int o = r*256 + tid;                 // 0..767
        int tok = o / 48, rr = o - tok*48;
        const float* wrow = xpw + rr*512;
        float acc = 0.f;
        #pragma unroll 8
        for (int dd = 0; dd < 512; ++dd)
            acc = fmaf(xsT[tok][dd], wrow[dd], acc);
        xd[tok][rr] = acc;
        if (rr >= 16) bcout[(size_t)(tok0+tok)*32 + (rr-16)] = acc;
    }
    __syncthreads();
    #pragma unroll
    for (int r = 0; r < 32; ++r) {
        int o = r*256 + tid;
        int tok = o >> 9, dd = o & 511;
        const float4* w4 = (const float4*)(dtw + dd*16);
        float acc = dtb[dd];
        #pragma unroll
        for (int q = 0; q < 4; ++q) {
            float4 w = w4[q];
            acc = fmaf(w.x, xd[tok][q*4+0], acc);
            acc = fmaf(w.y, xd[tok][q*4+1], acc);
            acc = fmaf(w.z, xd[tok][q*4+2], acc);
            acc = fmaf(w.w, xd[tok][q*4+3], acc);
        }
        // stable softplus
        float sp = fmaxf(acc, 0.f) + log1pf(__expf(-fabsf(acc)));
        dtv[(size_t)(tok0+tok)*512 + dd] = sp;
    }
}

// ---------- selective scan + gate ----------
// grid (32 d-blocks, 8 b), block 256 = 16 d x 16 s. yg may alias dtv.
__global__ __launch_bounds__(256) void k_scan(const float* __restrict__ dtv,
                                              const float* __restrict__ xs,
                                              const float* __restrict__ xz,    // z at +512
                                              const float* __restrict__ bc,
                                              const float* __restrict__ alog,
                                              const float* __restrict__ Dp,
                                              float* __restrict__ yg) {
    __shared__ float dtS[64][16];
    __shared__ float xsS[64][16];
    __shared__ float zS [64][16];
    __shared__ float bcS[64][32];
    const int tid = threadIdx.x;
    const int b  = blockIdx.y;
    const int d0 = blockIdx.x * 16;
    const int dl = tid >> 4;       // d_local
    const int s  = tid & 15;       // state idx
    const int d  = d0 + dl;
    const float A  = -__expf(alog[d*16 + s]);
    const float Dv = Dp[d];
    const int base = b << 10;
    float h = 0.f;
    for (int t0 = 0; t0 < 1024; t0 += 64) {
        __syncthreads();
        #pragma unroll
        for (int r = 0; r < 4; ++r) {
            int idx = r*256 + tid;          // 0..1023
            int tt = idx >> 4, c = idx & 15;
            size_t tok = base + t0 + tt;
            dtS[tt][c] = dtv[tok*512 + d0 + c];
            xsS[tt][c] = xs [tok*512 + d0 + c];
            zS [tt][c] = xz [tok*1024 + 512 + d0 + c];
        }
        #pragma unroll
        for (int r = 0; r < 8; ++r) {
            int idx = r*256 + tid;          // 0..2047
            int tt = idx >> 5, c = idx & 31;
            bcS[tt][c] = bc[(size_t)(base + t0 + tt)*32 + c];
        }
        __syncthreads();
        for (int tt = 0; tt < 64; ++tt) {
            float dt = dtS[tt][dl];
            float xt = xsS[tt][dl];
            float bv = bcS[tt][s];
            float cv = bcS[tt][16 + s];
            float dA = __expf(dt * A);
            h = fmaf(dA, h, dt * xt * bv);
            float p = h * cv;
            p += __shfl_xor(p, 1, 16);
            p += __shfl_xor(p, 2, 16);
            p += __shfl_xor(p, 4, 16);
            p += __shfl_xor(p, 8, 16);
            if (s == 0) {
                float z = zS[tt][dl];
                float g = z / (1.f + __expf(-z));
                yg[(size_t)(base + t0 + tt)*512 + d] = (p + xt * Dv) * g;
            }
        }
    }
}

// ---------- GEMM2: out[b,c,l] = sum_d Wot[d][c]*yg[tok][d] ----------
// M=8192 tokens (tile 128), N=256 c (tile 128), K=512 (step 8)
__global__ __launch_bounds__(256) void k_gemm_out(const float* __restrict__ yg,
                                                  const float* __restrict__ Wot,
                                                  float* __restrict__ out) {
    __shared__ float As[8][128];   // [d][token]
    __shared__ float Bs[8][128];   // [d][c]
    const int tid = threadIdx.x;
    const int m0 = blockIdx.y * 128;
    const int n0 = blockIdx.x * 128;
    const int tx = tid & 15;     // l (M) dim -> coalesced writes
    const int ty = tid >> 4;     // c (N) dim
    float acc[8][8] = {};        // [c][l]
    for (int d0 = 0; d0 < 512; d0 += 8) {
        __syncthreads();
        {
            int tok = tid >> 1, dp = (tid & 1) * 4;
            float4 v = *(const float4*)&yg[(size_t)(m0 + tok)*512 + d0 + dp];
            As[dp+0][tok] = v.x; As[dp+1][tok] = v.y;
            As[dp+2][tok] = v.z; As[dp+3][tok] = v.w;
        }
        #pragma unroll
        for (int r = 0; r < 4; ++r) {
            int idx = r*256 + tid;
            int kk = idx >> 7, col = idx & 127;
            Bs[kk][col] = Wot[(d0+kk)*256 + n0 + col];
        }
        __syncthreads();
        #pragma unroll
        for (int kk = 0; kk < 8; ++kk) {
            float a[8], bb[8];
            #pragma unroll
            for (int i = 0; i < 8; ++i) a[i]  = As[kk][tx*8 + i];
            #pragma unroll
            for (int j = 0; j < 8; ++j) bb[j] = Bs[kk][ty*8 + j];
            #pragma unroll
            for (int j = 0; j < 8; ++j)
                #pragma unroll
                for (int i = 0; i < 8; ++i)
                    acc[j][i] = fmaf(bb[j], a[i], acc[j][i]);
        }
    }
    const int b  = m0 >> 10;
    const int l0 = (m0 & 1023) + tx*8;
    #pragma unroll
    for (int j = 0; j < 8; ++j) {
        int c = n0 + ty*8 + j;
        float* orow = out + (((size_t)(b*256 + c)) << 10) + l0;
        #pragma unroll
        for (int i = 0; i < 8; ++i) orow[i] = acc[j][i];
    }
}

extern "C" void kernel_launch(void* const* d_in, const int* in_sizes, int n_in,
                              void* d_out, int out_size, void* d_ws, size_t ws_size,
                              hipStream_t stream) {
    const float* x    = (const float*)d_in[0];
    const float* pw   = (const float*)d_in[1];
    const float* pb   = (const float*)d_in[2];
    const float* ipw  = (const float*)d_in[3];
    const float* cw   = (const float*)d_in[4];
    const float* cb   = (const float*)d_in[5];
    const float* xpw  = (const float*)d_in[6];
    const float* dtw  = (const float*)d_in[7];
    const float* dtb  = (const float*)d_in[8];
    const float* alog = (const float*)d_in[9];
    const float* dvec = (const float*)d_in[10];
    const float* opw  = (const float*)d_in[11];
    float* out = (float*)d_out;
    float* ws  = (float*)d_ws;

    float* W2t = ws + OFF_W2T;
    float* b2  = ws + OFF_B2;
    float* Wot = ws + OFF_WOT;
    float* xzb = ws + OFF_XZ;
    float* xsb = ws + OFF_XS;
    float* dtv = ws + OFF_DT;
    float* bcb = ws + OFF_BC;
    float* ygb = dtv;   // alias: scan consumes dtv[t][d] before writing yg[t][d] (same owner block)

    k_w2t<<<1024, 256, 0, stream>>>(ipw, pw, W2t);
    k_b2 <<<4, 256, 0, stream>>>(ipw, pb, b2);
    k_wot<<<256, 512, 0, stream>>>(opw, Wot);
    k_gemm_xz<<<dim3(8, 64), 256, 0, stream>>>(x, W2t, b2, xzb);
    k_conv<<<NTOK*DI/256, 256, 0, stream>>>(xzb, (const float4*)cw, cb, xsb);
    k_xdbl<<<NTOK/16, 256, 0, stream>>>(xsb, xpw, dtw, dtb, bcb, dtv);
    k_scan<<<dim3(32, 8), 256, 0, stream>>>(dtv, xsb, xzb, bcb, alog, dvec, ygb);
    k_gemm_out<<<dim3(2, 64), 256, 0, stream>>>(ygb, Wot, out);
}

// Round 10
// 437.603 us; speedup vs baseline: 1.7327x; 1.7327x over previous
//
#include <hip/hip_runtime.h>

// ---------------- problem constants ----------------
#define BATCH 8
#define CDIM  256
#define LSEQ  1024           // H*W = 32*32
#define DI    512            // d_inner
#define DS    16             // d_state
#define DR    16             // dt_rank
#define NTOK  (BATCH*LSEQ)   // 8192 tokens

// scan chunking
#define TCH 32               // timesteps per chunk
#define NCH (LSEQ/TCH)       // 32 chunks

// workspace layout (float offsets)
#define OFF_W2T 0                       // (256 c, 1024 j)  c-major
#define OFF_B2  262144                  // (1024)
#define OFF_WOT 263168                  // (512 d, 256 c)   d-major
#define OFF_XZ  394240                  // (8192 tok, 1024) xm|z
#define OFF_XS  8782848                 // (8192 tok, 512)
#define OFF_DT  12977152                // (8192 tok, 512)  (aliased by ygate)
#define OFF_BC  17171456                // (8192 tok, 32)   B|C
// total 17433600 floats = 69.7 MB
// xpwT (512x48) and dtwT (16x512) ALIAS the W2t region: W2t is dead after
// k_gemm_xz, and the transposes launch after it on the same stream.

__device__ __forceinline__ float silu_f(float v) {
    return v / (1.f + __expf(-v));
}

// ---------- W2t[c][j] = sum_o in_proj_w[j,o]*proj_w[o,c] ----------
__global__ __launch_bounds__(256) void k_w2t(const float* __restrict__ ipw,
                                             const float* __restrict__ pw,
                                             float* __restrict__ W2t) {
    const int j = blockIdx.x;      // 0..1023
    const int c = threadIdx.x;     // 0..255
    float acc = 0.f;
    #pragma unroll 8
    for (int o = 0; o < 256; ++o)
        acc = fmaf(ipw[j*256 + o], pw[o*256 + c], acc);
    W2t[c*1024 + j] = acc;
}

// ---------- b2[j] = sum_o in_proj_w[j,o]*proj_b[o] ----------
__global__ __launch_bounds__(256) void k_b2(const float* __restrict__ ipw,
                                            const float* __restrict__ pb,
                                            float* __restrict__ b2) {
    const int j = blockIdx.x*256 + threadIdx.x;   // 0..1023
    float acc = 0.f;
    #pragma unroll 8
    for (int o = 0; o < 256; ++o)
        acc = fmaf(ipw[j*256 + o], pb[o], acc);
    b2[j] = acc;
}

// ---------- Wot[d][c] = out_proj_w[c][d] ----------
__global__ __launch_bounds__(512) void k_wot(const float* __restrict__ opw,
                                             float* __restrict__ Wot) {
    const int c = blockIdx.x;      // 0..255
    const int d = threadIdx.x;     // 0..511
    Wot[d*256 + c] = opw[c*512 + d];
}

// ---------- xpwT[dd*48+rr] = xpw[rr*512+dd]  (512x48, coalesced writes) ----
__global__ __launch_bounds__(256) void k_xpwT(const float* __restrict__ xpw,
                                              float* __restrict__ xpwT) {
    const int w = blockIdx.x*256 + threadIdx.x;   // 0..24575
    const int dd = w / 48, rr = w - dd*48;
    xpwT[w] = xpw[rr*512 + dd];
}

// ---------- dtwT[q*512+dd] = dtw[dd*16+q]  (16x512, coalesced writes) ------
__global__ __launch_bounds__(256) void k_dtwT(const float* __restrict__ dtw,
                                              float* __restrict__ dtwT) {
    const int w = blockIdx.x*256 + threadIdx.x;   // 0..8191
    const int q = w >> 9, dd = w & 511;
    dtwT[w] = dtw[dd*16 + q];
}

// ---------- GEMM1: xz[tok][j] = sum_c W2t[c][j]*x[b,c,l] + b2[j] ----------
__global__ __launch_bounds__(256) void k_gemm_xz(const float* __restrict__ x,
                                                 const float* __restrict__ W2t,
                                                 const float* __restrict__ b2,
                                                 float* __restrict__ xz) {
    __shared__ float As[8][128];
    __shared__ float Bs[8][128];
    const int tid = threadIdx.x;
    const int m0 = blockIdx.y * 128;          // token tile (within one b)
    const int n0 = blockIdx.x * 128;          // j tile
    const int b  = m0 >> 10;
    const int l0 = m0 & 1023;
    const float* xb = x + b*(256*1024);
    const int tx = tid & 15;                  // N dim
    const int ty = tid >> 4;                  // M dim
    float acc[8][8] = {};
    for (int c0 = 0; c0 < 256; c0 += 8) {
        __syncthreads();
        #pragma unroll
        for (int r = 0; r < 4; ++r) {
            int idx = r*256 + tid;
            int kk = idx >> 7, col = idx & 127;
            As[kk][col] = xb[(c0+kk)*1024 + l0 + col];
            Bs[kk][col] = W2t[(c0+kk)*1024 + n0 + col];
        }
        __syncthreads();
        #pragma unroll
        for (int kk = 0; kk < 8; ++kk) {
            float a[8], bb[8];
            #pragma unroll
            for (int i = 0; i < 8; ++i) a[i]  = As[kk][ty*8 + i];
            #pragma unroll
            for (int i = 0; i < 8; ++i) bb[i] = Bs[kk][tx*8 + i];
            #pragma unroll
            for (int i = 0; i < 8; ++i)
                #pragma unroll
                for (int j = 0; j < 8; ++j)
                    acc[i][j] = fmaf(a[i], bb[j], acc[i][j]);
        }
    }
    #pragma unroll
    for (int i = 0; i < 8; ++i) {
        const int tok = m0 + ty*8 + i;
        #pragma unroll
        for (int j = 0; j < 8; ++j) {
            const int jj = n0 + tx*8 + j;
            xz[(size_t)tok*1024 + jj] = acc[i][j] + b2[jj];
        }
    }
}

// ---------- depthwise causal conv(4) + bias + silu ----------
__global__ __launch_bounds__(256) void k_conv(const float* __restrict__ xz,
                                              const float4* __restrict__ cw4,
                                              const float* __restrict__ cb,
                                              float* __restrict__ xs) {
    const int idx = blockIdx.x*256 + threadIdx.x;   // 0..4194303
    const int d = idx & 511;
    const int t = (idx >> 9) & 1023;
    const int b = idx >> 19;
    const float4 w = cw4[d];
    const float* base = xz + ((size_t)(b << 10)) * 1024 + d;  // xm part (j<512)
    float acc = cb[d];
    if (t >= 3) {
        acc = fmaf(w.x, base[(size_t)(t-3)*1024], acc);
        acc = fmaf(w.y, base[(size_t)(t-2)*1024], acc);
        acc = fmaf(w.z, base[(size_t)(t-1)*1024], acc);
        acc = fmaf(w.w, base[(size_t)t*1024], acc);
    } else {
        const float wk[4] = {w.x, w.y, w.z, w.w};
        #pragma unroll
        for (int k = 0; k < 4; ++k) {
            int tt = t - 3 + k;
            if (tt >= 0) acc = fmaf(wk[k], base[(size_t)tt*1024], acc);
        }
    }
    xs[idx] = acc * (1.f / (1.f + __expf(-acc)));
}

// ---------- fused x_proj + dt_proj + softplus (transposed weights) ----------
// per block: 16 tokens. bc[tok][0:16]=B, [16:32]=C ; dtv=softplus(dt@dtw^T+dtb)
// Weight reads now coalesced: xpwT[dd][rr] (lanes span rr), dtwT[q][dd]
// (lanes span dd). FMA order identical to the validated version.
__global__ __launch_bounds__(256) void k_xdbl(const float* __restrict__ xs,
                                              const float* __restrict__ xpwT,  // (512,48)
                                              const float* __restrict__ dtwT,  // (16,512)
                                              const float* __restrict__ dtb,
                                              float* __restrict__ bcout,       // (tok,32)
                                              float* __restrict__ dtv) {
    __shared__ float xsT[16][512];
    __shared__ float xd[16][48];
    const int tid = threadIdx.x;
    const int tok0 = blockIdx.x * 16;
    #pragma unroll
    for (int r = 0; r < 32; ++r) {
        int idx = r*256 + tid;
        xsT[idx >> 9][idx & 511] = xs[(size_t)tok0*512 + idx];
    }
    __syncthreads();
    #pragma unroll
    for (int r = 0; r < 3; ++r) {
        int o = r*256 + tid;                 // 0..767
        int tok = o / 48, rr = o - tok*48;
        float acc = 0.f;
        #pragma unroll 8
        for (int dd = 0; dd < 512; ++dd)
            acc = fmaf(xsT[tok][dd], xpwT[dd*48 + rr], acc);
        xd[tok][rr] = acc;
        if (rr >= 16) bcout[(size_t)(tok0+tok)*32 + (rr-16)] = acc;
    }
    __syncthreads();
    #pragma unroll
    for (int r = 0; r < 32; ++r) {
        int o = r*256 + tid;
        int tok = o >> 9, dd = o & 511;
        float acc = dtb[dd];
        #pragma unroll
        for (int q = 0; q < 16; ++q)
            acc = fmaf(dtwT[q*512 + dd], xd[tok][q], acc);
        // stable softplus
        float sp = fmaxf(acc, 0.f) + log1pf(__expf(-fabsf(acc)));
        dtv[(size_t)(tok0+tok)*512 + dd] = sp;
    }
}

// ---------- selective scan + gate (restructured) ----------
// grid (32 d-blocks, 8 b), block 256 = 16 d x 16 s.
// Per 32-step chunk: reg-staged async loads -> LDS; sequential loop has NO
// cross-lane ops (p stored to padded LDS); parallel reduce+gate afterwards.
__global__ __launch_bounds__(256) void k_scan(const float* __restrict__ dtv,
                                              const float* __restrict__ xs,
                                              const float* __restrict__ xz,    // z at +512
                                              const float* __restrict__ bc,
                                              const float* __restrict__ alog,
                                              const float* __restrict__ Dp,
                                              float* __restrict__ yg) {
    __shared__ float dtS[TCH][16];
    __shared__ float xsS[TCH][16];
    __shared__ float zS [TCH][16];
    __shared__ float bcS[TCH][32];
    __shared__ float pS [TCH][16][17];   // padded: reduce reads bank-stride 17
    __shared__ float DpS[16];
    const int tid = threadIdx.x;
    const int b  = blockIdx.y;
    const int d0 = blockIdx.x * 16;
    const int dl = tid >> 4;       // d_local (compute phase)
    const int s  = tid & 15;       // state idx (compute phase)
    const float A = -__expf(alog[(d0 + dl)*16 + s]);
    if (tid < 16) DpS[tid] = Dp[d0 + tid];
    const int base = b << 10;

    float4 rA, rB, rC = {};

    // issue: async global float4 loads for chunk k into registers
    auto issue = [&](int k) {
        const int tb = base + k*TCH;
        {   // A: tid<128 -> dt (128 f4), else xs (128 f4)
            int i = tid & 127;
            int t = i >> 2, q = i & 3;
            const float* src = (tid < 128) ? dtv : xs;
            rA = *(const float4*)&src[(size_t)(tb + t)*512 + d0 + q*4];
        }
        if (tid < 128) {   // B: z (128 f4)
            int t = tid >> 2, q = tid & 3;
            rB = *(const float4*)&xz[(size_t)(tb + t)*1024 + 512 + d0 + q*4];
        } else {           // B: bc first half (128 f4)
            int i = tid - 128;
            int t = i >> 3, q = i & 7;
            rB = *(const float4*)&bc[(size_t)(tb + t)*32 + q*4];
        }
        if (tid < 128) {   // C: bc second half (128 f4)
            int i = tid + 128;
            int t = i >> 3, q = i & 7;
            rC = *(const float4*)&bc[(size_t)(tb + t)*32 + q*4];
        }
    };
    // commit: registers -> LDS
    auto commit = [&]() {
        {
            int i = tid & 127;
            int t = i >> 2, q = i & 3;
            float* dst = (tid < 128) ? &dtS[t][q*4] : &xsS[t][q*4];
            *(float4*)dst = rA;
        }
        if (tid < 128) {
            int t = tid >> 2, q = tid & 3;
            *(float4*)&zS[t][q*4] = rB;
        } else {
            int i = tid - 128;
            int t = i >> 3, q = i & 7;
            *(float4*)&bcS[t][q*4] = rB;
        }
        if (tid < 128) {
            int i = tid + 128;
            int t = i >> 3, q = i & 7;
            *(float4*)&bcS[t][q*4] = rC;
        }
    };

    issue(0);
    commit();
    __syncthreads();

    float h = 0.f;
    for (int k = 0; k < NCH; ++k) {
        if (k + 1 < NCH) issue(k + 1);     // loads fly during compute
        #pragma unroll 8
        for (int tt = 0; tt < TCH; ++tt) {
            float dt = dtS[tt][dl];
            float xt = xsS[tt][dl];
            float bv = bcS[tt][s];
            float cv = bcS[tt][16 + s];
            float dA = __expf(dt * A);     // off critical path (h-independent)
            h = fmaf(dA, h, dt * xt * bv); // the only true serial chain
            pS[tt][dl][s] = h * cv;        // fire-and-forget
        }
        __syncthreads();
        // reduce over s + D-term + silu gate; 512 (t,d) pairs, 2 rounds
        #pragma unroll
        for (int r = 0; r < 2; ++r) {
            int pair = r*256 + tid;
            int t = pair >> 4, dd = pair & 15;
            float sum = 0.f;
            #pragma unroll
            for (int q = 0; q < 16; ++q) sum += pS[t][dd][q];
            float xt = xsS[t][dd];
            float zz = zS[t][dd];
            float g  = zz / (1.f + __expf(-zz));
            yg[(size_t)(base + k*TCH + t)*512 + d0 + dd] = (sum + xt*DpS[dd]) * g;
        }
        __syncthreads();
        if (k + 1 < NCH) {
            commit();                       // vmcnt waits resolved long ago
            __syncthreads();
        }
    }
}

// ---------- GEMM2: out[b,c,l] = sum_d Wot[d][c]*yg[tok][d] ----------
__global__ __launch_bounds__(256) void k_gemm_out(const float* __restrict__ yg,
                                                  const float* __restrict__ Wot,
                                                  float* __restrict__ out) {
    __shared__ float As[8][128];   // [d][token]
    __shared__ float Bs[8][128];   // [d][c]
    const int tid = threadIdx.x;
    const int m0 = blockIdx.y * 128;
    const int n0 = blockIdx.x * 128;
    const int tx = tid & 15;     // l (M) dim -> coalesced writes
    const int ty = tid >> 4;     // c (N) dim
    float acc[8][8] = {};        // [c][l]
    for (int d0 = 0; d0 < 512; d0 += 8) {
        __syncthreads();
        {
            int tok = tid >> 1, dp = (tid & 1) * 4;
            float4 v = *(const float4*)&yg[(size_t)(m0 + tok)*512 + d0 + dp];
            As[dp+0][tok] = v.x; As[dp+1][tok] = v.y;
            As[dp+2][tok] = v.z; As[dp+3][tok] = v.w;
        }
        #pragma unroll
        for (int r = 0; r < 4; ++r) {
            int idx = r*256 + tid;
            int kk = idx >> 7, col = idx & 127;
            Bs[kk][col] = Wot[(d0+kk)*256 + n0 + col];
        }
        __syncthreads();
        #pragma unroll
        for (int kk = 0; kk < 8; ++kk) {
            float a[8], bb[8];
            #pragma unroll
            for (int i = 0; i < 8; ++i) a[i]  = As[kk][tx*8 + i];
            #pragma unroll
            for (int j = 0; j < 8; ++j) bb[j] = Bs[kk][ty*8 + j];
            #pragma unroll
            for (int j = 0; j < 8; ++j)
                #pragma unroll
                for (int i = 0; i < 8; ++i)
                    acc[j][i] = fmaf(bb[j], a[i], acc[j][i]);
        }
    }
    const int b  = m0 >> 10;
    const int l0 = (m0 & 1023) + tx*8;
    #pragma unroll
    for (int j = 0; j < 8; ++j) {
        int c = n0 + ty*8 + j;
        float* orow = out + (((size_t)(b*256 + c)) << 10) + l0;
        #pragma unroll
        for (int i = 0; i < 8; ++i) orow[i] = acc[j][i];
    }
}

extern "C" void kernel_launch(void* const* d_in, const int* in_sizes, int n_in,
                              void* d_out, int out_size, void* d_ws, size_t ws_size,
                              hipStream_t stream) {
    const float* x    = (const float*)d_in[0];
    const float* pw   = (const float*)d_in[1];
    const float* pb   = (const float*)d_in[2];
    const float* ipw  = (const float*)d_in[3];
    const float* cw   = (const float*)d_in[4];
    const float* cb   = (const float*)d_in[5];
    const float* xpw  = (const float*)d_in[6];
    const float* dtw  = (const float*)d_in[7];
    const float* dtb  = (const float*)d_in[8];
    const float* alog = (const float*)d_in[9];
    const float* dvec = (const float*)d_in[10];
    const float* opw  = (const float*)d_in[11];
    float* out = (float*)d_out;
    float* ws  = (float*)d_ws;

    float* W2t = ws + OFF_W2T;
    float* b2  = ws + OFF_B2;
    float* Wot = ws + OFF_WOT;
    float* xzb = ws + OFF_XZ;
    float* xsb = ws + OFF_XS;
    float* dtv = ws + OFF_DT;
    float* bcb = ws + OFF_BC;
    float* ygb = dtv;   // alias: scan consumes dtv[t][d] (staged) before writing yg[t][d]
    // xpwT/dtwT alias the W2t region (dead after k_gemm_xz; stream-serial order
    // guarantees the transposes run after k_gemm_xz's last read every replay)
    float* xpwT = ws + OFF_W2T;            // 24576 floats
    float* dtwT = ws + OFF_W2T + 24576;    // 8192 floats

    k_w2t<<<1024, 256, 0, stream>>>(ipw, pw, W2t);
    k_b2 <<<4, 256, 0, stream>>>(ipw, pb, b2);
    k_wot<<<256, 512, 0, stream>>>(opw, Wot);
    k_gemm_xz<<<dim3(8, 64), 256, 0, stream>>>(x, W2t, b2, xzb);
    k_xpwT<<<96, 256, 0, stream>>>(xpw, xpwT);
    k_dtwT<<<32, 256, 0, stream>>>(dtw, dtwT);
    k_conv<<<NTOK*DI/256, 256, 0, stream>>>(xzb, (const float4*)cw, cb, xsb);
    k_xdbl<<<NTOK/16, 256, 0, stream>>>(xsb, xpwT, dtwT, dtb, bcb, dtv);
    k_scan<<<dim3(32, 8), 256, 0, stream>>>(dtv, xsb, xzb, bcb, alog, dvec, ygb);
    k_gemm_out<<<dim3(2, 64), 256, 0, stream>>>(ygb, Wot, out);
}